// Round 5
// baseline (444.886 us; speedup 1.0000x reference)
//
#include <hip/hip_runtime.h>

// uDTW forward DP, R4: barrier-free producer->consumer wave pipeline.
// R3 post-mortem: per-phase wall ~3-5k cycles vs ~1.1k of chain work -> the
// 8-wave __syncthreads rendezvous every 16 steps dominates. Fix: decouple
// waves. Wave w depends ONLY on wave w-1; sync via per-wave monotone progress
// flags in LDS (spin + s_sleep), edge data in a WRITE-ONCE full-size array
// (edge[7][512], one float2 per boundary-row diagonal) so there is no ring
// reuse, no overwrite guard, and no circular wait (wave 0 never waits).
// Each wave computes only its 36 bursts with real cells; other bursts are
// flag-only fast-forwards. Cell math identical to R3 (absmax 0.0).

constexpr int N = 512;
constexpr int M = 512;
constexpr int BATCH = 32;
constexpr int NM = N + M;                  // 1024; diags d = 2..NM
constexpr int K = 16;                      // diagonals per burst
constexpr int NB = 64;                     // bursts cover d = 2..1025
constexpr float NL2E = -1.4426950408889634f;   // -log2(e)

__device__ __forceinline__ float lane_shr1(float x) {
  // lane n gets lane n-1's x; lane 0 gets 0 (overridden by caller).
  return __int_as_float(
      __builtin_amdgcn_update_dpp(0, __float_as_int(x), 0x138, 0xf, 0xf, true));
}

__global__ __launch_bounds__(512, 2)
void softdtw_fwd(const float* __restrict__ D,
                 const float* __restrict__ Sig,
                 float* __restrict__ out) {
  const int b = blockIdx.x;
  const int t = threadIdx.x;           // row r = t, cell i = t+1
  const int w = t >> 6;                // wave 0..7
  const int lane = t & 63;
  const bool l0 = (lane == 0);
  const float* Drow = D + ((size_t)b * N + t) * M;

  // Write-once boundary data: edge[w][c] = (exp(-R), Ddiag) of row 64w+63 at
  // its column c (diag d = 64w + 65 + c). Waves 0..6 publish, waves 1..7 read.
  __shared__ float2 edge[7][512];
  __shared__ volatile int prog[8];     // bursts completed per wave (monotone)
  if (t < 8) prog[t] = 0;

  // rolling window of my D row, prefetch depth 5
  float4 Q0 = *(const float4*)(Drow + 0);
  float4 Q1 = *(const float4*)(Drow + 4);
  float4 Q2 = *(const float4*)(Drow + 8);
  float4 Q3 = *(const float4*)(Drow + 12);
  float4 Q4 = *(const float4*)(Drow + 16);

  // carried state: own cell at d-1, neighbor (i-1) at d-2
  float eSelf = 0.f, dSelf = 0.f;                 // exp(-R[i,d-1]), Ddiag
  float eN2 = (t == 0) ? 1.f : 0.f, dN2 = 0.f;    // exp(-R[i-1,d-2]) (R[0,0]=0)

  // Sig contributes only via 4 elements at the final cell
  float sgA = 0.f, sg0 = 0.f, sg1 = 0.f, sg2 = 0.f;
  if (t == N - 1) {
    const float* Sb = Sig + (size_t)b * N * M;
    sgA = Sb[(size_t)(N - 1) * M + (M - 1)];
    sg0 = Sb[(size_t)(N - 2) * M + (M - 2)];
    sg1 = Sb[(size_t)(N - 2) * M + (M - 1)];
    sg2 = Sb[(size_t)(N - 1) * M + (M - 2)];
  }
  __syncthreads();                     // the ONLY block-wide barrier (init)

  // burst B covers diags [2+16B, 17+16B]; wave w's rows live on diags
  // [64w+2, 64w+577] -> active bursts B in [4w, 4w+35].
  const int Bl = 4 * w;
  const int Bh = 4 * w + 35;

  for (int B = 0; B < NB; ++B) {
    const bool active = (B >= Bl) && (B <= Bh);
    if (active) {
      if (w > 0) {
        // wait until wave w-1 finished burst B (its edges for diags
        // <= 17+16B are then in LDS); broadcast spin on one LDS word.
        while (prog[w - 1] < B + 1) __builtin_amdgcn_s_sleep(1);
        __threadfence_block();         // acquire: order edge reads below
      }
      const int d0 = 2 + B * K;
      // neighbor boundary values for diags d0-1 .. d0+K-2.
      // producer (w-1) stored diag dp at index dp - 64w - 1.
      float2 nbv[K];
      if (w > 0) {
        const int sbase = d0 - 2 - 64 * w;   // index for k=0 (diag d0-1)
        #pragma unroll
        for (int k = 0; k < K; ++k) {
          int s = sbase + k;
          int sc = s < 0 ? 0 : (s > 511 ? 511 : s);
          float2 v = edge[w - 1][sc];
          nbv[k] = (s >= 0 && s <= 511) ? v : make_float2(0.f, 0.f);
        }
      } else {
        #pragma unroll
        for (int k = 0; k < K; ++k) nbv[k] = make_float2(0.f, 0.f);
      }
      #pragma unroll
      for (int k = 0; k < K; ++k) {
        const int d = d0 + k;
        const int c = d - t - 2;        // my column this step (j = c+1)
        const bool valid = (c >= 0) && (c < M);
        // my D diagonal value (0 outside matrix)
        float ddd = 0.f;
        {
          const int ph = c & 3;
          float v = (ph == 0) ? Q0.x : (ph == 1) ? Q0.y : (ph == 2) ? Q0.z : Q0.w;
          if (valid) ddd = v;
          if (c >= 0 && ph == 3 && c < M - 1) {
            Q0 = Q1; Q1 = Q2; Q2 = Q3; Q3 = Q4;
            int cb = c + 17; if (cb > M - 4) cb = M - 4;
            Q4 = *(const float4*)(Drow + cb);
          }
        }
        // neighbor (i-1) at diag d-1: in-wave via DPP, wave boundary via nbv
        float sE = lane_shr1(eSelf);
        float sD = lane_shr1(dSelf);
        if (l0) { sE = nbv[k].x; sD = nbv[k].y; }
        const float e0 = eN2, e1 = sE, e2 = eSelf;
        const float sum = (e0 + e2) + e1;
        const float inv = __builtin_amdgcn_rcpf(sum);
        const float num  = fmaf(e0, dN2, fmaf(e1, sD, e2 * dSelf));
        const float numL = num * NL2E;
        const float dddL = ddd * NL2E;
        const float r2   = fmaf(inv, numL, dddL);
        float newE = __builtin_amdgcn_exp2f(r2);
        newE = valid ? newE : 0.f;      // masks NaN from sum==0 (rcp(0)=inf)
        if (d == NM && t == N - 1) {    // final cell (512,512)
          out[b] = fmaf(inv, num, ddd);                                  // rlast
          out[BATCH + b] = sgA + inv * (e0 * sg0 + e1 * sg1 + e2 * sg2); // slast
        }
        // rotate carries; publish boundary (write-once: index = my column c)
        eN2 = e1; dN2 = sD;
        eSelf = newE; dSelf = ddd;
        if (lane == 63 && w < 7 && valid)
          edge[w][c] = make_float2(newE, ddd);
      }
      __threadfence_block();           // release: edges before flag bump
    }
    if (lane == 63) prog[w] = B + 1;   // monotone progress
  }
}

extern "C" void kernel_launch(void* const* d_in, const int* in_sizes, int n_in,
                              void* d_out, int out_size, void* d_ws, size_t ws_size,
                              hipStream_t stream) {
  const float* D   = (const float*)d_in[0];
  const float* Sig = (const float*)d_in[1];
  float* out = (float*)d_out;
  softdtw_fwd<<<dim3(BATCH), dim3(512), 0, stream>>>(D, Sig, out);
}